// Round 11
// baseline (4531.905 us; speedup 1.0000x reference)
//
#include <hip/hip_runtime.h>
#include <hip/hip_bf16.h>

#define N_   64
#define T_   1024
#define IN_  64
#define H1_  512
#define H2_  256
#define NG   4      // batch groups of 16 rows
#define NLB  16     // merged LSTM blocks per group (32 L1 units + 16 L2 units each)
#define RING 8      // h1 ring depth (per group)
#define RING2 4     // h2 ring depth (per group)
#define SENT 0xAAAAAAAAu   // == harness ws poison; bf16 pair ~ -1.2e-13

typedef __bf16 bf16x8 __attribute__((ext_vector_type(8)));
typedef float  f32x4  __attribute__((ext_vector_type(4)));
typedef unsigned int u32x4 __attribute__((ext_vector_type(4)));
typedef unsigned short u16x8 __attribute__((ext_vector_type(8)));
typedef unsigned long long u64;
typedef __hip_bfloat16 bf16_t;

// ---------------- workspace layout (bytes) ----------------
#define OFF_FLGP  0u          // 4*16*128 = 8192 (L2-progress flags, worker gating)
#define OFF_QUE   12288u      // work-queue counter
#define ZERO_BYTES 16384u
#define OFF_H1R   16384u      // h1 ring: 4g*8slot*16row*512*2 = 524288
#define OFF_H2R   540672u     // h2 ring: 4g*4slot*16row*256*2 = 131072
#define OFF_XB    671744u     // 8388608
#define OFF_W1    9060352u    // 2359296
#define OFF_W2    11419648u   // 1572864
#define OFF_B1    12992512u   // 8192
#define OFF_B2    13000704u   // 4096
#define OFF_FC1W  13004800u   // 131072
#define OFF_FC2W  13135872u   // 16384
#define OFF_HS2   13152256u   // 64*1024*256*2 = 33554432 -> 46706688
#define OFF_BURN  46706688u   // dummy sink (never actually written)

__device__ __forceinline__ bf16x8 ld16(const bf16_t* p) {
  u32x4 u = *reinterpret_cast<const u32x4*>(p);
  return __builtin_bit_cast(bf16x8, u);
}
__device__ __forceinline__ u64 ld64_mall(const void* p) {
  return __hip_atomic_load((const u64*)p, __ATOMIC_RELAXED, __HIP_MEMORY_SCOPE_AGENT);
}
__device__ __forceinline__ void st4_mall(bf16_t* p, unsigned v) {
  __hip_atomic_store((unsigned*)p, v, __ATOMIC_RELAXED, __HIP_MEMORY_SCOPE_AGENT);
}
__device__ __forceinline__ unsigned ldflag(unsigned* p) {
  return __hip_atomic_load(p, __ATOMIC_RELAXED, __HIP_MEMORY_SCOPE_AGENT);
}
__device__ __forceinline__ bool sentok(u64 w) {
  return ((unsigned)w != SENT) && ((unsigned)(w >> 32) != SENT);
}
__device__ __forceinline__ f32x4 mfma_bf16(bf16x8 a, bf16x8 b, f32x4 c) {
  return __builtin_amdgcn_mfma_f32_16x16x32_bf16(a, b, c, 0, 0, 0);
}
__device__ __forceinline__ float sigf(float x) { return 1.f / (1.f + __expf(-x)); }
__device__ __forceinline__ float tanh_fast(float x) {
  float e = __expf(-2.f * fabsf(x));
  float r = (1.f - e) / (1.f + e);
  return x < 0.f ? -r : r;
}
__device__ __forceinline__ unsigned short bf16_bits(float v) {
  __hip_bfloat16 b = __float2bfloat16(v);
  return *reinterpret_cast<unsigned short*>(&b);
}

// ---------------- setup: bf16 conversion / packing ----------------
__global__ void setup_kernel(const float* __restrict__ x,
    const float* __restrict__ Wih1, const float* __restrict__ Whh1,
    const float* __restrict__ bih1, const float* __restrict__ bhh1,
    const float* __restrict__ Wih2, const float* __restrict__ Whh2,
    const float* __restrict__ bih2, const float* __restrict__ bhh2,
    const float* __restrict__ fc1w, const float* __restrict__ fc2w,
    char* __restrict__ ws)
{
  bf16_t* xb = (bf16_t*)(ws + OFF_XB);
  bf16_t* w1 = (bf16_t*)(ws + OFF_W1);
  bf16_t* w2 = (bf16_t*)(ws + OFF_W2);
  float*  b1 = (float*)(ws + OFF_B1);
  float*  b2 = (float*)(ws + OFF_B2);
  bf16_t* f1 = (bf16_t*)(ws + OFF_FC1W);
  bf16_t* f2 = (bf16_t*)(ws + OFF_FC2W);
  const long E0 = 4194304, E1 = E0 + 1179648, E2 = E1 + 786432,
             E3 = E2 + 2048, E4 = E3 + 1024, E5 = E4 + 65536, E6 = E5 + 8192;
  for (long i = blockIdx.x * (long)blockDim.x + threadIdx.x; i < E6;
       i += (long)gridDim.x * blockDim.x) {
    if (i < E0) {
      xb[i] = __float2bfloat16(x[i]);
    } else if (i < E1) {                       // W1[j][k] = [Wih1 | Whh1]
      long idx = i - E0; long j = idx / 576, k = idx % 576;
      float v = (k < 64) ? Wih1[j * 64 + k] : Whh1[j * 512 + (k - 64)];
      w1[idx] = __float2bfloat16(v);
    } else if (i < E2) {                       // W2[j][k] = [Wih2 | Whh2]
      long idx = i - E1; long j = idx / 768, k = idx % 768;
      float v = (k < 512) ? Wih2[j * 512 + k] : Whh2[j * 256 + (k - 512)];
      w2[idx] = __float2bfloat16(v);
    } else if (i < E3) {
      long idx = i - E2; b1[idx] = bih1[idx] + bhh1[idx];
    } else if (i < E4) {
      long idx = i - E3; b2[idx] = bih2[idx] + bhh2[idx];
    } else if (i < E5) {
      long idx = i - E4; f1[idx] = __float2bfloat16(fc1w[idx]);
    } else {                                   // fc2 padded to 64 rows
      long idx = i - E5; long j = idx / 128, k = idx % 128;
      f2[idx] = __float2bfloat16(j < 51 ? fc2w[j * 128 + k] : 0.f);
    }
  }
}

// ============================================================================
// fused persistent kernel: 64 merged LSTM blocks (L1+L2) + 192 workers.
// Data-sentinel sync on MALL-bypass rings; no flags on the recurrent path.
// ============================================================================
__global__ __launch_bounds__(256, 1) void fused_kernel(char* __restrict__ ws,
    const float* __restrict__ fc1b, const float* __restrict__ fc2b,
    const float* __restrict__ fc3w, const float* __restrict__ fc3b,
    float* __restrict__ dout)
{
  const bf16_t* xb  = (const bf16_t*)(ws + OFF_XB);
  const bf16_t* W1  = (const bf16_t*)(ws + OFF_W1);
  const bf16_t* W2  = (const bf16_t*)(ws + OFF_W2);
  const float*  b1  = (const float*)(ws + OFF_B1);
  const float*  b2  = (const float*)(ws + OFF_B2);
  bf16_t* h1r = (bf16_t*)(ws + OFF_H1R);
  bf16_t* h2r = (bf16_t*)(ws + OFF_H2R);
  bf16_t* hs2 = (bf16_t*)(ws + OFF_HS2);
  unsigned* flagP = (unsigned*)(ws + OFF_FLGP);   // [g][u] stride 32 words

  __shared__ __align__(16) char smem[55296];

  const int tid  = threadIdx.x;
  const int wave = tid >> 6;
  const int lane = tid & 63;
  const int l15  = lane & 15;
  const int quad = lane >> 4;
  const int bx   = blockIdx.x;
  const f32x4 z = {0.f, 0.f, 0.f, 0.f};

  if (bx < NG * NLB) {
    // ===== merged LSTM block: group g; L1 units [u0,u0+32); L2 units [u02,u02+16)
    const int g = bx >> 4, u = bx & 15, u0 = u * 32, u02 = u * 16;
    bf16_t* hstage  = (bf16_t*)smem;              // [16][584]  x | h1(t-1)
    bf16_t* h2stage = (bf16_t*)(smem + 18688);    // [16][264]  h2(t-2)
    float*  gbuf1   = (float*)(smem + 27136);     // [64][33]
    float*  gbuf2   = (float*)(smem + 35584);     // [64][17]

    bf16x8 wf1[18][2];
    #pragma unroll
    for (int i = 0; i < 18; ++i)
      #pragma unroll
      for (int nt = 0; nt < 2; ++nt)
        wf1[i][nt] = ld16(W1 + (size_t)(wave * H1_ + u0 + nt * 16 + l15) * 576 + i * 32 + quad * 8);
    bf16x8 wf2[24];
    #pragma unroll
    for (int i = 0; i < 24; ++i)
      wf2[i] = ld16(W2 + (size_t)(wave * H2_ + u02 + l15) * 768 + i * 32 + quad * 8);

    const int sr = tid >> 4;            // batch row (staging + elementwise)
    const int myp = tid & 15;           // slice index
    const int row = sr, ui = myp * 2;   // L1: 2 units
    const int unit2 = myp;              // L2: 1 unit
    const int nrow = g * 16 + row;
    unsigned* myflag = flagP + (g * NLB + u) * 32;

    float b1i[2], b1f[2], b1g[2], b1o[2], creg1[2];
    #pragma unroll
    for (int j = 0; j < 2; ++j) {
      int ug = u0 + ui + j;
      b1i[j] = b1[ug];          b1f[j] = b1[H1_ + ug];
      b1g[j] = b1[2*H1_ + ug];  b1o[j] = b1[3*H1_ + ug];
      creg1[j] = 0.f;
    }
    float b2i, b2f, b2g, b2o, creg2 = 0.f;
    { int ug2 = u02 + unit2;
      b2i = b2[ug2]; b2f = b2[H2_ + ug2]; b2g = b2[2*H2_ + ug2]; b2o = b2[3*H2_ + ug2]; }

    // defense-in-depth SENT init (poison is already SENT)
    #pragma unroll
    for (int s = 0; s < RING; ++s)
      st4_mall(h1r + ((size_t)(g * RING + s) * 16 + row) * 512 + u0 + ui, SENT);
    if (!(tid & 1))
      #pragma unroll
      for (int s = 0; s < RING2; ++s)
        st4_mall(h2r + ((size_t)(g * RING2 + s) * 16 + row) * 256 + u02 + unit2, SENT);

    u64 pf1[8], pf2[4];
    #pragma unroll 1
    for (int t = 0; t <= T_; ++t) {
      // ---- A: staging (validate prefetch, else poll)
      if (t < T_) {
        u64 xv = *(const u64*)(xb + ((size_t)(g*16 + sr) * T_ + t) * IN_ + myp * 4);
        *(u64*)(hstage + sr * 584 + myp * 4) = xv;
      }
      if (t == 0) {
        #pragma unroll
        for (int k = 0; k < 8; ++k)
          *(u64*)(hstage + sr * 584 + 64 + myp * 32 + k * 4) = 0ull;
      } else {
        const u64* s1 = (const u64*)(h1r + ((size_t)(g * RING + ((t-1) & 7)) * 16 + sr) * 512 + myp * 32);
        bool good = true;
        #pragma unroll
        for (int k = 0; k < 8; ++k) good &= sentok(pf1[k]);
        if (!good) {
          for (;;) {
            #pragma unroll
            for (int k = 0; k < 8; ++k) pf1[k] = ld64_mall(s1 + k);
            bool ok = true;
            #pragma unroll
            for (int k = 0; k < 8; ++k) ok &= sentok(pf1[k]);
            if (ok) break;
          }
        }
        #pragma unroll
        for (int k = 0; k < 8; ++k)
          *(u64*)(hstage + sr * 584 + 64 + myp * 32 + k * 4) = pf1[k];
      }
      if (t >= 2) {
        const u64* s2 = (const u64*)(h2r + ((size_t)(g * RING2 + ((t-2) & 3)) * 16 + sr) * 256 + myp * 16);
        bool good = true;
        #pragma unroll
        for (int k = 0; k < 4; ++k) good &= sentok(pf2[k]);
        if (!good) {
          for (;;) {
            #pragma unroll
            for (int k = 0; k < 4; ++k) pf2[k] = ld64_mall(s2 + k);
            bool ok = true;
            #pragma unroll
            for (int k = 0; k < 4; ++k) ok &= sentok(pf2[k]);
            if (ok) break;
          }
        }
        #pragma unroll
        for (int k = 0; k < 4; ++k)
          *(u64*)(h2stage + sr * 264 + myp * 16 + k * 4) = pf2[k];
      } else if (t == 1) {
        #pragma unroll
        for (int k = 0; k < 4; ++k)
          *(u64*)(h2stage + sr * 264 + myp * 16 + k * 4) = 0ull;
      }
      __syncthreads();   // staging visible; drains prev-step MALL stores (vmcnt0)
      // deferred worker-gating publish: hs2 rows 0..t-2 stored AND drained
      if (tid == 0 && t >= 2)
        __hip_atomic_store(myflag, (unsigned)(t - 1), __ATOMIC_RELAXED, __HIP_MEMORY_SCOPE_AGENT);
      // ring resets (epoch-safe: peers' progress proven via observed data)
      if (t < T_) {
        st4_mall(h1r + ((size_t)(g * RING + ((t+1) & 7)) * 16 + row) * 512 + u0 + ui, SENT);
        if (!(tid & 1))
          st4_mall(h2r + ((size_t)(g * RING2 + ((t+1) & 3)) * 16 + row) * 256 + u02 + unit2, SENT);
      }
      // ---- E: MFMA (L1 for step t; L2 for step t-1) — 6 independent chains
      if (t < T_) {
        f32x4 acc[2] = {z, z}, acd[2] = {z, z};
        #pragma unroll
        for (int ki = 0; ki < 9; ++ki) {
          bf16x8 aw = ld16(hstage + l15 * 584 + ki * 32 + quad * 8);
          acc[0] = mfma_bf16(aw, wf1[ki][0], acc[0]);
          acc[1] = mfma_bf16(aw, wf1[ki][1], acc[1]);
        }
        #pragma unroll
        for (int ki = 9; ki < 18; ++ki) {
          bf16x8 aw = ld16(hstage + l15 * 584 + ki * 32 + quad * 8);
          acd[0] = mfma_bf16(aw, wf1[ki][0], acd[0]);
          acd[1] = mfma_bf16(aw, wf1[ki][1], acd[1]);
        }
        acc[0] += acd[0]; acc[1] += acd[1];
        #pragma unroll
        for (int nt = 0; nt < 2; ++nt)
          #pragma unroll
          for (int r = 0; r < 4; ++r)
            gbuf1[(wave * 16 + quad * 4 + r) * 33 + nt * 16 + l15] = acc[nt][r];
      }
      if (t >= 1) {
        f32x4 a2a = z, a2b = z;
        #pragma unroll
        for (int ki = 0; ki < 12; ++ki) {
          bf16x8 aw = ld16(hstage + l15 * 584 + 64 + ki * 32 + quad * 8);
          a2a = mfma_bf16(aw, wf2[ki], a2a);
        }
        #pragma unroll
        for (int ki = 12; ki < 24; ++ki) {
          bf16x8 aw = (ki < 16)
              ? ld16(hstage + l15 * 584 + 64 + ki * 32 + quad * 8)
              : ld16(h2stage + l15 * 264 + (ki - 16) * 32 + quad * 8);
          a2b = mfma_bf16(aw, wf2[ki], a2b);
        }
        a2a += a2b;
        #pragma unroll
        for (int r = 0; r < 4; ++r)
          gbuf2[(wave * 16 + quad * 4 + r) * 17 + l15] = a2a[r];
      }
      __syncthreads();
      // ---- G: gates + stores
      if (t < T_) {
        unsigned pack = 0;
        float hv[2];
        #pragma unroll
        for (int j = 0; j < 2; ++j) {
          int col = ui + j;
          float iv = sigf(gbuf1[(0*16 + row) * 33 + col] + b1i[j]);
          float fv = sigf(gbuf1[(1*16 + row) * 33 + col] + b1f[j]);
          float gv = tanh_fast(gbuf1[(2*16 + row) * 33 + col] + b1g[j]);
          float ov = sigf(gbuf1[(3*16 + row) * 33 + col] + b1o[j]);
          float c = fv * creg1[j] + iv * gv;
          creg1[j] = c;
          float h = ov * tanh_fast(c);
          hv[j] = h;
          pack |= (unsigned)bf16_bits(h) << (16 * j);
        }
        st4_mall(h1r + ((size_t)(g * RING + (t & 7)) * 16 + row) * 512 + u0 + ui, pack);
        if (t == T_ - 1) {
          #pragma unroll
          for (int j = 0; j < 2; ++j) {
            dout[65536 + nrow * H1_ + u0 + ui + j] = hv[j];
            dout[98304 + nrow * H1_ + u0 + ui + j] = creg1[j];
          }
        }
      }
      if (t >= 1) {
        const int tm1 = t - 1;
        float iv = sigf(gbuf2[(0*16 + row) * 17 + unit2] + b2i);
        float fv = sigf(gbuf2[(1*16 + row) * 17 + unit2] + b2f);
        float gv = tanh_fast(gbuf2[(2*16 + row) * 17 + unit2] + b2g);
        float ov = sigf(gbuf2[(3*16 + row) * 17 + unit2] + b2o);
        float c2 = fv * creg2 + iv * gv;
        creg2 = c2;
        float h2v = ov * tanh_fast(c2);
        unsigned mb = bf16_bits(h2v);
        unsigned ob = __shfl_xor(mb, 1);
        if (!(tid & 1)) {          // dword-granular stores keep sentinel sound
          unsigned pk = mb | (ob << 16);
          st4_mall(h2r + ((size_t)(g * RING2 + (tm1 & 3)) * 16 + row) * 256 + u02 + unit2, pk);
          st4_mall(hs2 + ((size_t)nrow * T_ + tm1) * H2_ + u02 + unit2, pk);
        }
        if (tm1 == T_ - 1) {
          dout[131072 + nrow * H2_ + u02 + unit2] = h2v;
          dout[147456 + nrow * H2_ + u02 + unit2] = creg2;
        }
      }
      // ---- prefetch next step's exchange data (validated at next staging)
      if (t < T_) {
        const u64* nx1 = (const u64*)(h1r + ((size_t)(g * RING + (t & 7)) * 16 + sr) * 512 + myp * 32);
        #pragma unroll
        for (int k = 0; k < 8; ++k) pf1[k] = ld64_mall(nx1 + k);
        if (t >= 1) {
          const u64* nx2 = (const u64*)(h2r + ((size_t)(g * RING2 + ((t-1) & 3)) * 16 + sr) * 256 + myp * 16);
          #pragma unroll
          for (int k = 0; k < 4; ++k) pf2[k] = ld64_mall(nx2 + k);
        }
      }
    }
    __syncthreads();   // drain final hs2 stores
    if (tid == 0)
      __hip_atomic_store(myflag, (unsigned)T_, __ATOMIC_RELAXED, __HIP_MEMORY_SCOPE_AGENT);
  }

  // ================= attention + FC worker (all blocks; LSTM joins late) ====
  __syncthreads();
  {
    const bf16_t* f1w = (const bf16_t*)(ws + OFF_FC1W);
    const bf16_t* f2w = (const bf16_t*)(ws + OFF_FC2W);
    unsigned* queue = (unsigned*)(ws + OFF_QUE);
    unsigned short* vtile = (unsigned short*)smem;     // [256][72] swizzled, s-loop
    bf16_t* plds   = (bf16_t*)(smem + 36864);          // wave w: +w*1152, [16][72]
    bf16_t* ctxlds = (bf16_t*)smem;                    // [64][264] post-loop
    bf16_t* act1   = (bf16_t*)(smem + 36864);          // [64][136] post-loop
    float*  act2   = (float*)smem;                     // [64][68]
    volatile int* itemslot = (volatile int*)(smem + 55040);
    float burn = 1.0f;

    for (;;) {
      if (tid == 0) *itemslot = (int)atomicAdd(queue, 1u);
      __syncthreads();
      const int item = *itemslot;
      __syncthreads();
      if (item >= 1024) break;
      const int qt = item >> 6, n = item & 63, q0 = qt * 64, gg = n >> 4;

      // wait for hs2[n][0 .. q0+63] (all 16 producers of group gg), FMA burn
      {
        const int need = q0 + 64;
        if (tid < 64) {
          unsigned* p = (lane < NLB) ? flagP + (gg * NLB + lane) * 32 : nullptr;
          bool ok = (p == nullptr) || ((int)ldflag(p) >= need);
          while (!__all(ok)) {
            #pragma unroll
            for (int k = 0; k < 128; ++k) burn = fmaf(burn, 1.0000001f, 1e-7f);
            ok = (p == nullptr) || ((int)ldflag(p) >= need);
          }
        }
        __syncthreads();
      }

      bf16x8 aq[8];
      #pragma unroll
      for (int ks = 0; ks < 8; ++ks)
        aq[ks] = ld16(hs2 + ((size_t)n * T_ + q0 + wave * 16 + l15) * H2_ + ks * 32 + quad * 8);
      f32x4 o[16];
      #pragma unroll
      for (int ct = 0; ct < 16; ++ct) o[ct] = z;
      float m_run[4], l_run[4];
      #pragma unroll
      for (int r = 0; r < 4; ++r) { m_run[r] = -1e30f; l_run[r] = 0.f; }
      bf16_t* pw = plds + wave * 1152;

      #pragma unroll 1
      for (int st = 0; st <= qt; ++st) {
        const int s0 = st * 64;
        __syncthreads();    // vtile reuse safe
        // stage V-tile transposed, XOR-swizzled s-blocks (conflict-free writes)
        #pragma unroll
        for (int it = 0; it < 8; ++it) {
          int s  = (tid >> 3) + (it & 1) * 32;
          int c0 = (tid & 7) * 8 + (it >> 1) * 64;
          u16x8 v = *reinterpret_cast<const u16x8*>(
              (const unsigned short*)hs2 + ((size_t)n * T_ + s0 + s) * H2_ + c0);
          #pragma unroll
          for (int j = 0; j < 8; ++j) {
            int ch = c0 + j;
            int sw = (s & 7) | ((((s >> 3) ^ (ch >> 3)) & 7) << 3);
            vtile[ch * 72 + sw] = v[j];
          }
        }
        __syncthreads();
        f32x4 sc[4] = {z, z, z, z};
        #pragma unroll
        for (int ks = 0; ks < 8; ++ks) {
          #pragma unroll
          for (int nt = 0; nt < 4; ++nt) {
            bf16x8 bk = ld16(hs2 + ((size_t)n * T_ + s0 + nt * 16 + l15) * H2_ + ks * 32 + quad * 8);
            sc[nt] = mfma_bf16(aq[ks], bk, sc[nt]);
          }
        }
        if (st == qt) {
          int qg = q0 + wave * 16 + quad * 4;
          #pragma unroll
          for (int nt = 0; nt < 4; ++nt) {
            int sg = s0 + nt * 16 + l15;
            #pragma unroll
            for (int r = 0; r < 4; ++r)
              if (sg > qg + r) sc[nt][r] = -1e30f;
          }
        }
        float alpha[4];
        #pragma unroll
        for (int r = 0; r < 4; ++r) {
          float tm = fmaxf(fmaxf(sc[0][r], sc[1][r]), fmaxf(sc[2][r], sc[3][r]));
          tm = fmaxf(tm, __shfl_xor(tm, 1, 16));
          tm = fmaxf(tm, __shfl_xor(tm, 2, 16));
          tm = fmaxf(tm, __shfl_xor(tm, 4, 16));
          tm = fmaxf(tm, __shfl_xor(tm, 8, 16));
          float mnew = fmaxf(m_run[r], tm);
          alpha[r] = __expf(m_run[r] - mnew);
          m_run[r] = mnew;
          float ts = 0.f;
          #pragma unroll
          for (int nt = 0; nt < 4; ++nt) {
            float p = __expf(sc[nt][r] - mnew);
            sc[nt][r] = p;
            ts += p;
          }
          ts += __shfl_xor(ts, 1, 16);
          ts += __shfl_xor(ts, 2, 16);
          ts += __shfl_xor(ts, 4, 16);
          ts += __shfl_xor(ts, 8, 16);
          l_run[r] = l_run[r] * alpha[r] + ts;
        }
        #pragma unroll
        for (int ct = 0; ct < 16; ++ct)
          #pragma unroll
          for (int r = 0; r < 4; ++r)
            o[ct][r] *= alpha[r];
        #pragma unroll
        for (int nt = 0; nt < 4; ++nt)
          #pragma unroll
          for (int r = 0; r < 4; ++r)
            pw[(quad * 4 + r) * 72 + nt * 16 + l15] = __float2bfloat16(sc[nt][r]);
        #pragma unroll
        for (int ks2 = 0; ks2 < 2; ++ks2) {
          bf16x8 ap = ld16(pw + l15 * 72 + ks2 * 32 + quad * 8);
          #pragma unroll
          for (int ct = 0; ct < 16; ++ct) {
            int ch = ct * 16 + l15;
            int blk = ((ks2 * 4 + quad) ^ (ch >> 3)) & 7;
            bf16x8 bv = ld16((bf16_t*)vtile + ch * 72 + blk * 8);
            o[ct] = mfma_bf16(ap, bv, o[ct]);
          }
        }
      }
      __syncthreads();
      float inv[4];
      #pragma unroll
      for (int r = 0; r < 4; ++r) inv[r] = 1.f / l_run[r];
      #pragma unroll
      for (int ct = 0; ct < 16; ++ct)
        #pragma unroll
        for (int r = 0; r < 4; ++r)
          ctxlds[(wave * 16 + quad * 4 + r) * 264 + ct * 16 + l15] =
              __float2bfloat16(o[ct][r] * inv[r]);
      __syncthreads();

      // fc1: K=512 (ctx|hs2) -> 128 ch, wave owns 32 channels
      f32x4 a1[4][2];
      #pragma unroll
      for (int mt = 0; mt < 4; ++mt) { a1[mt][0] = z; a1[mt][1] = z; }
      #pragma unroll
      for (int ks = 0; ks < 16; ++ks) {
        bf16x8 af[4];
        if (ks < 8) {
          #pragma unroll
          for (int mt = 0; mt < 4; ++mt)
            af[mt] = ld16(ctxlds + (mt * 16 + l15) * 264 + ks * 32 + quad * 8);
        } else {
          #pragma unroll
          for (int mt = 0; mt < 4; ++mt)
            af[mt] = ld16(hs2 + ((size_t)n * T_ + q0 + mt * 16 + l15) * H2_ + (ks - 8) * 32 + quad * 8);
        }
        #pragma unroll
        for (int nt = 0; nt < 2; ++nt) {
          bf16x8 bw = ld16(f1w + (size_t)(wave * 32 + nt * 16 + l15) * 512 + ks * 32 + quad * 8);
          #pragma unroll
          for (int mt = 0; mt < 4; ++mt)
            a1[mt][nt] = mfma_bf16(af[mt], bw, a1[mt][nt]);
        }
      }
      #pragma unroll
      for (int mt = 0; mt < 4; ++mt)
        #pragma unroll
        for (int nt = 0; nt < 2; ++nt)
          #pragma unroll
          for (int r = 0; r < 4; ++r) {
            int ch = wave * 32 + nt * 16 + l15;
            float v = a1[mt][nt][r] + fc1b[ch];
            act1[(mt * 16 + quad * 4 + r) * 136 + ch] = __float2bfloat16(fmaxf(v, 0.f));
          }
      __syncthreads();

      // fc2: K=128 -> 51 ch (padded 64)
      f32x4 a2[4] = {z, z, z, z};
      #pragma unroll
      for (int ks = 0; ks < 4; ++ks) {
        bf16x8 bw = ld16(f2w + (wave * 16 + l15) * 128 + ks * 32 + quad * 8);
        #pragma unroll
        for (int mt = 0; mt < 4; ++mt) {
          bf16x8 af = ld16(act1 + (mt * 16 + l15) * 136 + ks * 32 + quad * 8);
          a2[mt] = mfma_bf16(af, bw, a2[mt]);
        }
      }
      __syncthreads();
      #pragma unroll
      for (int mt = 0; mt < 4; ++mt)
        #pragma unroll
        for (int r = 0; r < 4; ++r) {
          int ch = wave * 16 + l15;
          int rw = mt * 16 + quad * 4 + r;
          float v = a2[mt][r] + (ch < 51 ? fc2b[ch] : 0.f);
          act2[rw * 68 + ch] = fmaxf(v, 0.f);
        }
      __syncthreads();
      if (tid < 64) {
        float s = fc3b[0];
        for (int c = 0; c < 51; ++c) s += act2[tid * 68 + c] * fc3w[c];
        dout[(size_t)n * T_ + q0 + tid] = s;
      }
      __syncthreads();   // LDS reuse + itemslot reuse
    }
    if (burn == 0.1234567f)   // never true; keeps burn alive
      ((float*)(ws + OFF_BURN))[tid] = burn;
  }
}

extern "C" void kernel_launch(void* const* d_in, const int* in_sizes, int n_in,
                              void* d_out, int out_size, void* d_ws, size_t ws_size,
                              hipStream_t stream) {
  (void)in_sizes; (void)n_in; (void)out_size; (void)ws_size;
  const float* x    = (const float*)d_in[0];
  const float* Wih1 = (const float*)d_in[1];
  const float* Whh1 = (const float*)d_in[2];
  const float* bih1 = (const float*)d_in[3];
  const float* bhh1 = (const float*)d_in[4];
  const float* Wih2 = (const float*)d_in[5];
  const float* Whh2 = (const float*)d_in[6];
  const float* bih2 = (const float*)d_in[7];
  const float* bhh2 = (const float*)d_in[8];
  const float* fc1w = (const float*)d_in[9];
  const float* fc1b = (const float*)d_in[10];
  const float* fc2w = (const float*)d_in[11];
  const float* fc2b = (const float*)d_in[12];
  const float* fc3w = (const float*)d_in[13];
  const float* fc3b = (const float*)d_in[14];
  char* ws  = (char*)d_ws;
  float* out = (float*)d_out;

  hipMemsetAsync(ws, 0, ZERO_BYTES, stream);   // flags + work queue (NOT h rings:
                                               // their 0xAA poison == SENT)
  setup_kernel<<<2048, 256, 0, stream>>>(x, Wih1, Whh1, bih1, bhh1,
                                         Wih2, Whh2, bih2, bhh2, fc1w, fc2w, ws);
  fused_kernel<<<256, 256, 0, stream>>>(ws, fc1b, fc2b, fc3w, fc3b, out);
}